// Round 12
// baseline (12.890 us; speedup 1.0000x reference)
//
#include <hip/hip_runtime.h>

#define NP 8
#define NB 160
#define NA 32
#define NATYPE 16
#define NPOLY 11
#define MIN_SEP 4
#define DVALID (1 << 16)
#define NPROD (NP * NB)            // 1280 producer wgs
#define SLOTS_PER_POSE (NB * 4)    // 640 wave partials per pose
#define MAGICU 0x48424F4Eu         // != 0, != 0xAAAAAAAA

// Producer wgs (blockIdx < NPROD): r7 main body, per-wave tagged partial.
// Reducer wgs (blockIdx = NPROD + pose): spin-consume own pose's 640 slots.
__global__ __launch_bounds__(256) void hbond_kernel(
    const float* __restrict__ coords,        // (P, N*A, 3)
    const int*   __restrict__ coord_off,     // (P, N)
    const int*   __restrict__ block_type,    // (P, N)
    const int*   __restrict__ min_sep,       // (P, N, N)
    const int*   __restrict__ n_donH,        // (BT,)
    const int*   __restrict__ n_acc,         // (BT,)
    const int*   __restrict__ donH_inds,     // (BT, 4)
    const int*   __restrict__ acc_inds,      // (BT, 8)
    const int*   __restrict__ donor_type,    // (BT, 4)
    const int*   __restrict__ acceptor_type, // (BT, 8)
    const int*   __restrict__ acceptor_hyb,  // (BT, 8)
    const float* __restrict__ pair_params,   // (256, 3)
    const float* __restrict__ pair_poly,     // (256, 11)
    const float* __restrict__ gp,            // (4,)
    unsigned long long* __restrict__ slots,  // ws: NP*640 tagged partials
    float*       __restrict__ out)           // (P,)
{
    const int t  = threadIdx.x;
    const int wv = t >> 6, ln = t & 63;

    // ================= reducer wgs =================
    if (blockIdx.x >= NPROD) {
        const int pose = blockIdx.x - NPROD;
        unsigned long long* base = slots + pose * SLOTS_PER_POSE;
        __shared__ float rsum[4];

        float acc = 0.0f;
        for (int idx = t; idx < SLOTS_PER_POSE; idx += 256) {
            unsigned long long v;
            for (;;) {
                v = __hip_atomic_load(&base[idx], __ATOMIC_RELAXED,
                                      __HIP_MEMORY_SCOPE_AGENT);
                if ((unsigned int)(v >> 32) == MAGICU) break;
                __builtin_amdgcn_s_sleep(1);
            }
            acc += __int_as_float((int)(unsigned int)(v & 0xffffffffull));
        }
        #pragma unroll
        for (int off = 32; off >= 1; off >>= 1)
            acc += __shfl_down(acc, off, 64);
        if (ln == 0) rsum[wv] = acc;
        __syncthreads();
        if (t == 0) out[pose] = rsum[0] + rsum[1] + rsum[2] + rsum[3];
        // reset slots for next graph replay (kernels serialize on stream)
        for (int idx = t; idx < SLOTS_PER_POSE; idx += 256)
            __hip_atomic_store(&base[idx], 0ull,
                               __ATOMIC_RELAXED, __HIP_MEMORY_SCOPE_AGENT);
        return;
    }

    // ================= producer wgs (r7 body) =================
    const int p  = blockIdx.x / NB;
    const int b1 = blockIdx.x - p * NB;

    __shared__ int4 b2info[NB];   // (bt2, off2, n_acc, 0) 2560 B
    __shared__ int  b2list[NB];   //  640 B
    __shared__ int  wc[4];

    const float cut  = gp[0];
    const float emin = gp[1];

    // ---- per-b2 metadata + pair_ok (t < 160) ----
    bool ok = false;
    if (t < NB) {
        const int bt2  = block_type[p * NB + t];
        const int off2 = coord_off[p * NB + t];
        const int na   = n_acc[bt2];
        ok = (t != b1) && (min_sep[(p * NB + b1) * NB + t] >= MIN_SEP);
        b2info[t] = make_int4(bt2, off2, na, 0);
    }

    // ---- donors for b1 (wave-uniform scalar loads) ----
    const int bt1  = block_type[p * NB + b1];
    const int off1 = coord_off[p * NB + b1];
    const int nd   = n_donH[bt1];
    float4 dv[4];
    #pragma unroll
    for (int dn = 0; dn < 4; ++dn) {
        const int hatom = donH_inds[bt1 * 4 + dn];
        const int dbase = donor_type[bt1 * 4 + dn] * NATYPE;
        const float* Hc = coords + (size_t)(p * (NB * NA) + off1 + hatom) * 3;
        dv[dn] = make_float4(Hc[0], Hc[1], Hc[2],
                             __int_as_float((dbase & 0xff) | ((dn < nd) ? DVALID : 0)));
    }

    // ---- compact b2 list (single ballot round) ----
    const unsigned long long m = __ballot(ok);
    if (ln == 0) wc[wv] = __popcll(m);
    __syncthreads();

    int pre = 0, cnt = 0;
    #pragma unroll
    for (int w = 0; w < 4; ++w) {
        cnt += wc[w];
        if (w < wv) pre += wc[w];
    }
    if (ok) b2list[pre + __popcll(m & ((1ull << ln) - 1ull))] = t;
    __syncthreads();

    // ---- main loop over cnt*8 acceptor slots ----
    float energy = 0.0f;
    const int cnt8 = cnt * 8;
    for (int i = t; i < cnt8; i += 256) {
        const int b2 = b2list[i >> 3];
        const int a  = i & 7;
        const int4 info = b2info[b2];

        float hd0 = 0, hd1 = 0, hd2 = 0, hd3 = 0;
        int   hp0 = 0, hp1 = 0, hp2 = 0, hp3 = 0;
        int   nh = 0, hyb = 0;

        if (a < info.z) {
            const int ai    = acc_inds[info.x * 8 + a];
            const int atype = acceptor_type[info.x * 8 + a];
            hyb             = acceptor_hyb[info.x * 8 + a];
            const float* Ac = coords + (size_t)(p * (NB * NA) + info.y + ai) * 3;
            const float ax = Ac[0], ay = Ac[1], az = Ac[2];

            #pragma unroll
            for (int dn = 0; dn < 4; ++dn) {
                const int dbits = __float_as_int(dv[dn].w);
                if (!(dbits & DVALID)) continue;   // wave-uniform
                const float dx = dv[dn].x - ax;
                const float dy = dv[dn].y - ay;
                const float dz = dv[dn].z - az;
                const float dd = sqrtf(dx * dx + dy * dy + dz * dz + 1e-12f);
                if (dd < cut) {
                    const int pp = (dbits & 0xff) + atype;
                    hd3 = (nh == 3) ? dd : hd3;  hp3 = (nh == 3) ? pp : hp3;
                    hd2 = (nh == 2) ? dd : hd2;  hp2 = (nh == 2) ? pp : hp2;
                    hd1 = (nh == 1) ? dd : hd1;  hp1 = (nh == 1) ? pp : hp1;
                    hd0 = (nh == 0) ? dd : hd0;  hp0 = (nh == 0) ? pp : hp0;
                    ++nh;
                }
            }
        }

        // rare Horner path (~1% of slots pass the distance filter)
        #pragma unroll
        for (int h = 0; h < 4; ++h) {
            if (!__any(h < nh)) break;
            if (h < nh) {
                const float dd = (h == 0) ? hd0 : (h == 1) ? hd1 : (h == 2) ? hd2 : hd3;
                const int   pp = (h == 0) ? hp0 : (h == 1) ? hp1 : (h == 2) ? hp2 : hp3;
                const float* c = pair_poly + pp * NPOLY;
                float ev = c[0];
                #pragma unroll
                for (int kk = 1; kk < NPOLY; ++kk) ev = ev * dd + c[kk];
                const float w = pair_params[pp * 3 + hyb];
                ev = fmaxf(fminf(ev, 0.0f), emin);
                energy += w * ev;
            }
        }
    }

    // ---- wave-local reduce -> tagged partial (pure store, agent scope) ----
    #pragma unroll
    for (int off = 32; off >= 1; off >>= 1)
        energy += __shfl_down(energy, off, 64);
    if (ln == 0) {
        const unsigned long long v =
            ((unsigned long long)MAGICU << 32) |
            (unsigned long long)(unsigned int)__float_as_int(energy);
        __hip_atomic_store(&slots[(p * NB + b1) * 4 + wv], v,
                           __ATOMIC_RELAXED, __HIP_MEMORY_SCOPE_AGENT);
    }
}

extern "C" void kernel_launch(void* const* d_in, const int* in_sizes, int n_in,
                              void* d_out, int out_size, void* d_ws, size_t ws_size,
                              hipStream_t stream) {
    const float* coords        = (const float*)d_in[0];
    // d_in[1] (dispatch) is the full (p, b1, b2) meshgrid — derived from blockIdx.
    const int*   coord_off     = (const int*)  d_in[2];
    const int*   block_type    = (const int*)  d_in[3];
    const int*   min_sep       = (const int*)  d_in[4];
    const int*   n_donH        = (const int*)  d_in[5];
    const int*   n_acc         = (const int*)  d_in[6];
    const int*   donH_inds     = (const int*)  d_in[7];
    const int*   acc_inds      = (const int*)  d_in[8];
    const int*   donor_type    = (const int*)  d_in[9];
    const int*   acceptor_type = (const int*)  d_in[10];
    const int*   acceptor_hyb  = (const int*)  d_in[11];
    const float* pair_params   = (const float*)d_in[12];
    const float* pair_poly     = (const float*)d_in[13];
    const float* gp            = (const float*)d_in[14];
    unsigned long long* slots  = (unsigned long long*)d_ws;  // NP*640*8 = 40960 B
    float*       out           = (float*)d_out;

    hbond_kernel<<<NPROD + NP, 256, 0, stream>>>(
        coords, coord_off, block_type, min_sep,
        n_donH, n_acc, donH_inds, acc_inds,
        donor_type, acceptor_type, acceptor_hyb,
        pair_params, pair_poly, gp, slots, out);
}

// Round 13
// 12.337 us; speedup vs baseline: 1.0449x; 1.0449x over previous
//
#include <hip/hip_runtime.h>

#define NP 8
#define NB 160
#define NA 32
#define NATYPE 16
#define NPOLY 11
#define MIN_SEP 4
#define DVALID (1 << 16)
#define NWG (NP * NB)        // 1280

// main: one wg per (pose, b1). Writes one partial per wg to ws (pure write).
__global__ __launch_bounds__(256) void hbond_main(
    const float* __restrict__ coords,        // (P, N*A, 3)
    const int*   __restrict__ coord_off,     // (P, N)
    const int*   __restrict__ block_type,    // (P, N)
    const int*   __restrict__ min_sep,       // (P, N, N)
    const int*   __restrict__ n_donH,        // (BT,)
    const int*   __restrict__ n_acc,         // (BT,)
    const int*   __restrict__ donH_inds,     // (BT, 4)
    const int*   __restrict__ acc_inds,      // (BT, 8)
    const int*   __restrict__ donor_type,    // (BT, 4)
    const int*   __restrict__ acceptor_type, // (BT, 8)
    const int*   __restrict__ acceptor_hyb,  // (BT, 8)
    const float* __restrict__ pair_params,   // (256, 3)
    const float* __restrict__ pair_poly,     // (256, 11)
    const float* __restrict__ gp,            // (4,)
    float*       __restrict__ partials)      // (NWG,)
{
    const int t  = threadIdx.x;
    const int p  = blockIdx.x / NB;
    const int b1 = blockIdx.x - p * NB;

    __shared__ int4  b2info[NB];   // (bt2, off2, n_acc, pad) 2560 B
    __shared__ int   b2list[NB];   //  640 B
    __shared__ int   wc[4];
    __shared__ float wsum[4];

    const float cut  = gp[0];
    const float emin = gp[1];

    // ---- per-b2 metadata + pair_ok (t < 160) ----
    bool ok = false;
    if (t < NB) {
        const int bt2  = block_type[p * NB + t];
        const int off2 = coord_off[p * NB + t];
        const int na   = n_acc[bt2];
        ok = (t != b1) && (min_sep[(p * NB + b1) * NB + t] >= MIN_SEP);
        b2info[t] = make_int4(bt2, off2, na, 0);
    }

    // ---- donors for b1 (wave-uniform scalar loads) ----
    const int bt1  = block_type[p * NB + b1];
    const int off1 = coord_off[p * NB + b1];
    const int nd   = n_donH[bt1];
    float4 dv[4];
    #pragma unroll
    for (int dn = 0; dn < 4; ++dn) {
        const int hatom = donH_inds[bt1 * 4 + dn];
        const int dbase = donor_type[bt1 * 4 + dn] * NATYPE;
        const float* Hc = coords + (size_t)(p * (NB * NA) + off1 + hatom) * 3;
        dv[dn] = make_float4(Hc[0], Hc[1], Hc[2],
                             __int_as_float((dbase & 0xff) | ((dn < nd) ? DVALID : 0)));
    }

    // ---- compact b2 list (single ballot round) ----
    const unsigned long long m = __ballot(ok);
    const int wv = t >> 6, ln = t & 63;
    if (ln == 0) wc[wv] = __popcll(m);
    __syncthreads();

    int pre = 0, cnt = 0;
    #pragma unroll
    for (int w = 0; w < 4; ++w) {
        cnt += wc[w];
        if (w < wv) pre += wc[w];
    }
    if (ok) b2list[pre + __popcll(m & ((1ull << ln) - 1ull))] = t;
    __syncthreads();

    // ---- main loop over cnt*8 acceptor slots ----
    float energy = 0.0f;
    const int cnt8 = cnt * 8;
    for (int i = t; i < cnt8; i += 256) {
        const int b2 = b2list[i >> 3];
        const int a  = i & 7;
        const int4 info = b2info[b2];

        float hd0 = 0, hd1 = 0, hd2 = 0, hd3 = 0;
        int   hp0 = 0, hp1 = 0, hp2 = 0, hp3 = 0;
        int   nh = 0, hyb = 0;

        if (a < info.z) {
            const int ai    = acc_inds[info.x * 8 + a];
            const int atype = acceptor_type[info.x * 8 + a];
            hyb             = acceptor_hyb[info.x * 8 + a];
            const float* Ac = coords + (size_t)(p * (NB * NA) + info.y + ai) * 3;
            const float ax = Ac[0], ay = Ac[1], az = Ac[2];

            #pragma unroll
            for (int dn = 0; dn < 4; ++dn) {
                const int dbits = __float_as_int(dv[dn].w);
                if (!(dbits & DVALID)) continue;   // wave-uniform
                const float dx = dv[dn].x - ax;
                const float dy = dv[dn].y - ay;
                const float dz = dv[dn].z - az;
                const float dd = sqrtf(dx * dx + dy * dy + dz * dz + 1e-12f);
                if (dd < cut) {
                    const int pp = (dbits & 0xff) + atype;
                    hd3 = (nh == 3) ? dd : hd3;  hp3 = (nh == 3) ? pp : hp3;
                    hd2 = (nh == 2) ? dd : hd2;  hp2 = (nh == 2) ? pp : hp2;
                    hd1 = (nh == 1) ? dd : hd1;  hp1 = (nh == 1) ? pp : hp1;
                    hd0 = (nh == 0) ? dd : hd0;  hp0 = (nh == 0) ? pp : hp0;
                    ++nh;
                }
            }
        }

        // rare Horner path (~1% of slots)
        #pragma unroll
        for (int h = 0; h < 4; ++h) {
            if (!__any(h < nh)) break;
            if (h < nh) {
                const float dd = (h == 0) ? hd0 : (h == 1) ? hd1 : (h == 2) ? hd2 : hd3;
                const int   pp = (h == 0) ? hp0 : (h == 1) ? hp1 : (h == 2) ? hp2 : hp3;
                const float* c = pair_poly + pp * NPOLY;
                float ev = c[0];
                #pragma unroll
                for (int k = 1; k < NPOLY; ++k) ev = ev * dd + c[k];
                const float w = pair_params[pp * 3 + hyb];
                ev = fmaxf(fminf(ev, 0.0f), emin);
                energy += w * ev;
            }
        }
    }

    // ---- reduce 256 -> 1 partial (pure write, no init needed) ----
    #pragma unroll
    for (int off = 32; off >= 1; off >>= 1)
        energy += __shfl_down(energy, off, 64);
    if (ln == 0) wsum[wv] = energy;
    __syncthreads();
    if (t == 0) partials[blockIdx.x] = wsum[0] + wsum[1] + wsum[2] + wsum[3];
}

// reduce: 1 wg; wave wv sums poses 2wv, 2wv+1 (160 partials each). Pure writes.
__global__ __launch_bounds__(256) void hbond_reduce(
    const float* __restrict__ partials, float* __restrict__ out)
{
    const int wv = threadIdx.x >> 6, ln = threadIdx.x & 63;
    #pragma unroll
    for (int q = 0; q < 2; ++q) {
        const int pose = wv * 2 + q;
        const float* base = partials + pose * NB;
        float v = base[ln] + base[64 + ln] + ((ln < 32) ? base[128 + ln] : 0.0f);
        #pragma unroll
        for (int off = 32; off >= 1; off >>= 1)
            v += __shfl_down(v, off, 64);
        if (ln == 0) out[pose] = v;
    }
}

extern "C" void kernel_launch(void* const* d_in, const int* in_sizes, int n_in,
                              void* d_out, int out_size, void* d_ws, size_t ws_size,
                              hipStream_t stream) {
    const float* coords        = (const float*)d_in[0];
    // d_in[1] (dispatch) is the full (p, b1, b2) meshgrid — derived from blockIdx.
    const int*   coord_off     = (const int*)  d_in[2];
    const int*   block_type    = (const int*)  d_in[3];
    const int*   min_sep       = (const int*)  d_in[4];
    const int*   n_donH        = (const int*)  d_in[5];
    const int*   n_acc         = (const int*)  d_in[6];
    const int*   donH_inds     = (const int*)  d_in[7];
    const int*   acc_inds      = (const int*)  d_in[8];
    const int*   donor_type    = (const int*)  d_in[9];
    const int*   acceptor_type = (const int*)  d_in[10];
    const int*   acceptor_hyb  = (const int*)  d_in[11];
    const float* pair_params   = (const float*)d_in[12];
    const float* pair_poly     = (const float*)d_in[13];
    const float* gp            = (const float*)d_in[14];
    float*       partials      = (float*)d_ws;   // NWG floats = 5120 B
    float*       out           = (float*)d_out;

    hbond_main<<<NWG, 256, 0, stream>>>(
        coords, coord_off, block_type, min_sep,
        n_donH, n_acc, donH_inds, acc_inds,
        donor_type, acceptor_type, acceptor_hyb,
        pair_params, pair_poly, gp, partials);

    hbond_reduce<<<1, 256, 0, stream>>>(partials, out);
}